// Round 4
// baseline (611.037 us; speedup 1.0000x reference)
//
#include <hip/hip_runtime.h>

// NAGNNActor fused pipeline.
// fp32 GIN math with bf16 intermediate storage; bf16-MFMA final GEMM
// (lin1 400x256 dominates FLOPs: 53.7 GF).
// Graph: fixed 32x32 grid 4-neighbor stencil (edge_index input ignored; it is
// deterministic). GIN eps=-1 => agg = plain neighbor sum.
// ws layout (193.2 MiB total — was 385 MiB fp32; prime crash suspect r3):
//   x1[ROWS*128]bf16 | x2 | x3 | logits[ROWS]f32 | w1t[256*400]bf16
// Numerics: bf16 storage of LN+ReLU outputs (~0.2% rel) + bf16-input/fp32-acc
// MFMA on lin1+lin2; softmax crushes abs output error to ~1e-4.

namespace {
constexpr int NN = 1024;          // nodes per sample (32x32)
constexpr int BATCH = 256;
constexpr int FIN = 16;
constexpr int HID = 128;
constexpr int ROWS = BATCH * NN;  // 262144
}

typedef __attribute__((ext_vector_type(8))) short bf16x8;   // 8 bf16 = 4 VGPR
typedef __attribute__((ext_vector_type(4))) float f32x4;

__device__ inline unsigned short f2bf(float f) {  // RNE fp32->bf16
  union { float f; unsigned u; } v; v.f = f;
  unsigned r = v.u + 0x7FFFu + ((v.u >> 16) & 1u);
  return (unsigned short)(r >> 16);
}

// ---------------- Prepass: w1[400][256] f32 -> w1t[256][400] bf16 ------------
// B-fragments of mfma_16x16x32_bf16 need 8 consecutive-k elements per col,
// so W must be stored col-major (k contiguous). Tiny (400 KB read), L2-hot.
__global__ __launch_bounds__(256) void k_prep(
    const float* __restrict__ w1, unsigned short* __restrict__ w1t)
{
  const int c = blockIdx.x;               // 256 cols
  for (int k = threadIdx.x; k < 400; k += 256)
    w1t[(size_t)c * 400 + k] = f2bf(w1[(size_t)k * 256 + c]);
}

// ---------------- Layer 0: stencil(obs) @ W0[16,128] + LN + ReLU -------------
// 64 rows/block, 256 thr. Wave w owns rows w*16..w*16+15; lane owns cols
// (lane, lane+64). W0 (16x2 per lane) lives in registers. LN = wave shfl.
__global__ __launch_bounds__(256) void k_layer0(
    const float* __restrict__ obs,
    const float* __restrict__ w,  const float* __restrict__ bias,
    const float* __restrict__ g,  const float* __restrict__ be,
    unsigned short* __restrict__ xout)
{
  __shared__ float aggs[64][FIN];   // 4 KB
  const int t = threadIdx.x;
  const int lane = t & 63, wave = t >> 6;
  const int row0 = blockIdx.x * 64;
  const int b = row0 >> 10;
  const int n0 = row0 & (NN - 1);

  {  // stage stencil sums: one float4 per thread ([64 rows][4 quads])
    const int rl = t >> 2;
    const int kq = (t & 3) * 4;
    const int n = n0 + rl;
    const int gi = n >> 5, gj = n & 31;
    const float* base = obs + (size_t)b * NN * FIN + kq;
    float4 s = make_float4(0.f, 0.f, 0.f, 0.f);
    if (gj > 0)  { float4 v = *(const float4*)(base + (size_t)(n - 1)  * FIN); s.x += v.x; s.y += v.y; s.z += v.z; s.w += v.w; }
    if (gj < 31) { float4 v = *(const float4*)(base + (size_t)(n + 1)  * FIN); s.x += v.x; s.y += v.y; s.z += v.z; s.w += v.w; }
    if (gi > 0)  { float4 v = *(const float4*)(base + (size_t)(n - 32) * FIN); s.x += v.x; s.y += v.y; s.z += v.z; s.w += v.w; }
    if (gi < 31) { float4 v = *(const float4*)(base + (size_t)(n + 32) * FIN); s.x += v.x; s.y += v.y; s.z += v.z; s.w += v.w; }
    *(float4*)&aggs[rl][kq] = s;
  }

  const int c0 = lane, c1 = lane + 64;
  float wr0[FIN], wr1[FIN];
  #pragma unroll
  for (int k = 0; k < FIN; ++k) { wr0[k] = w[k * HID + c0]; wr1[k] = w[k * HID + c1]; }
  const float bias0 = bias[c0], bias1 = bias[c1];
  const float gg0 = g[c0], gg1 = g[c1], bb0 = be[c0], bb1 = be[c1];
  __syncthreads();

  #pragma unroll 4
  for (int rr = 0; rr < 16; ++rr) {
    const int rl = wave * 16 + rr;
    float y0 = bias0, y1 = bias1;
    #pragma unroll
    for (int kq = 0; kq < FIN; kq += 4) {
      float4 a = *(const float4*)&aggs[rl][kq];
      y0 = fmaf(a.x, wr0[kq+0], y0);  y1 = fmaf(a.x, wr1[kq+0], y1);
      y0 = fmaf(a.y, wr0[kq+1], y0);  y1 = fmaf(a.y, wr1[kq+1], y1);
      y0 = fmaf(a.z, wr0[kq+2], y0);  y1 = fmaf(a.z, wr1[kq+2], y1);
      y0 = fmaf(a.w, wr0[kq+3], y0);  y1 = fmaf(a.w, wr1[kq+3], y1);
    }
    float s = y0 + y1, ss = y0 * y0 + y1 * y1;
    #pragma unroll
    for (int m = 1; m < 64; m <<= 1) { s += __shfl_xor(s, m); ss += __shfl_xor(ss, m); }
    const float mu  = s * (1.f / 128.f);
    const float var = ss * (1.f / 128.f) - mu * mu;
    const float inv = rsqrtf(var + 1e-5f);
    const float o0 = fmaxf(fmaf((y0 - mu) * inv, gg0, bb0), 0.f);
    const float o1 = fmaxf(fmaf((y1 - mu) * inv, gg1, bb1), 0.f);
    unsigned short* op = xout + (size_t)(row0 + rl) * HID;
    op[c0] = f2bf(o0); op[c1] = f2bf(o1);
  }
}

// ---------------- Layers 1/2: stencil(x) @ W[128,128] + LN + ReLU ------------
// 32 rows/block, 256 thr. Wave w owns rows w*8..w*8+7 (LN stays in-wave);
// lane owns cols (lane, lane+64). W (fp32) staged in two 64x128 LDS chunks.
// x in/out is bf16 (storage only; math fp32).
__global__ __launch_bounds__(256) void k_gin128(
    const unsigned short* __restrict__ xin, const float* __restrict__ w,
    const float* __restrict__ bias, const float* __restrict__ g,
    const float* __restrict__ be, unsigned short* __restrict__ xout)
{
  __shared__ float aggs[32][HID];   // 16 KB
  __shared__ float wls[64][HID];    // 32 KB
  const int t = threadIdx.x;
  const int lane = t & 63, wave = t >> 6;
  const int row0 = blockIdx.x * 32;
  const int b = row0 >> 10, n0 = row0 & (NN - 1);

  {  // stage stencil sums: thread covers 16 contiguous k of one row
    const int rl = t >> 3;
    const int kb = (t & 7) * 16;
    const int n = n0 + rl;
    const int gi = n >> 5, gj = n & 31;
    const unsigned short* base = xin + (size_t)b * NN * HID + kb;
    float s[16];
    #pragma unroll
    for (int j = 0; j < 16; ++j) s[j] = 0.f;
    auto addn = [&](int nb) {
      const unsigned short* p = base + (size_t)nb * HID;
      const uint4 u0 = *(const uint4*)p;         // 8 bf16
      const uint4 u1 = *(const uint4*)(p + 8);   // 8 bf16
      const unsigned uu[8] = {u0.x, u0.y, u0.z, u0.w, u1.x, u1.y, u1.z, u1.w};
      #pragma unroll
      for (int j = 0; j < 8; ++j) {
        union { unsigned u; float f; } lo, hi;
        lo.u = uu[j] << 16;
        hi.u = uu[j] & 0xFFFF0000u;
        s[2 * j]     += lo.f;
        s[2 * j + 1] += hi.f;
      }
    };
    if (gj > 0)  addn(n - 1);
    if (gj < 31) addn(n + 1);
    if (gi > 0)  addn(n - 32);
    if (gi < 31) addn(n + 32);
    #pragma unroll
    for (int j = 0; j < 16; j += 4)
      *(float4*)&aggs[rl][kb + j] = *(const float4*)&s[j];
  }

  const int c0 = lane, c1 = lane + 64;
  const int rwb = wave * 8;
  float acc[8][2];
  #pragma unroll
  for (int r = 0; r < 8; ++r) { acc[r][0] = 0.f; acc[r][1] = 0.f; }

  for (int kc = 0; kc < HID; kc += 64) {
    __syncthreads();
    #pragma unroll
    for (int i2 = 0; i2 < 8; ++i2) {   // stage W chunk [64][128]
      const int f = t + 256 * i2;
      const int kl = f >> 5;
      const int cq = (f & 31) * 4;
      *(float4*)&wls[kl][cq] = *(const float4*)(w + (size_t)(kc + kl) * HID + cq);
    }
    __syncthreads();
    for (int kq = 0; kq < 64; kq += 4) {
      float4 a[8];
      #pragma unroll
      for (int r = 0; r < 8; ++r) a[r] = *(const float4*)&aggs[rwb + r][kc + kq];
      const float wa0 = wls[kq+0][c0], wa1 = wls[kq+0][c1];
      const float wb0 = wls[kq+1][c0], wb1 = wls[kq+1][c1];
      const float wc0 = wls[kq+2][c0], wc1 = wls[kq+2][c1];
      const float wd0 = wls[kq+3][c0], wd1 = wls[kq+3][c1];
      #pragma unroll
      for (int r = 0; r < 8; ++r) {
        acc[r][0] = fmaf(a[r].x, wa0, acc[r][0]);
        acc[r][0] = fmaf(a[r].y, wb0, acc[r][0]);
        acc[r][0] = fmaf(a[r].z, wc0, acc[r][0]);
        acc[r][0] = fmaf(a[r].w, wd0, acc[r][0]);
        acc[r][1] = fmaf(a[r].x, wa1, acc[r][1]);
        acc[r][1] = fmaf(a[r].y, wb1, acc[r][1]);
        acc[r][1] = fmaf(a[r].z, wc1, acc[r][1]);
        acc[r][1] = fmaf(a[r].w, wd1, acc[r][1]);
      }
    }
  }

  const float bias0 = bias[c0], bias1 = bias[c1];
  const float gg0 = g[c0], gg1 = g[c1], bb0 = be[c0], bb1 = be[c1];
  #pragma unroll
  for (int r = 0; r < 8; ++r) {
    const float y0 = acc[r][0] + bias0, y1 = acc[r][1] + bias1;
    float s = y0 + y1, ss = y0 * y0 + y1 * y1;
    #pragma unroll
    for (int m = 1; m < 64; m <<= 1) { s += __shfl_xor(s, m); ss += __shfl_xor(ss, m); }
    const float mu  = s * (1.f / 128.f);
    const float var = ss * (1.f / 128.f) - mu * mu;
    const float inv = rsqrtf(var + 1e-5f);
    const float o0 = fmaxf(fmaf((y0 - mu) * inv, gg0, bb0), 0.f);
    const float o1 = fmaxf(fmaf((y1 - mu) * inv, gg1, bb1), 0.f);
    unsigned short* op = xout + (size_t)(row0 + rwb + r) * HID;
    op[c0] = f2bf(o0); op[c1] = f2bf(o1);
  }
}

// ------- Final (bf16 MFMA): concat[obs,x1,x2,x3] @ lin1 + BN + ReLU + lin2 ---
// 2048 blocks x 512 thr. Block: 128 rows x 256 cols, writes FULL logits.
// Wave w: rows (w>>2)*64, cols (w&3)*64 -> 4 A-frags, 4 B-frags, 16 MFMA/step.
// 13 K-steps: step0 = obs K=16 (zero-padded to 32), steps 1..12 = x1/x2/x3
// (already bf16 -> staging is a raw uint4 copy).
// mfma_f32_16x16x32_bf16 layouts (learn_hip m89/m97 verified):
//   A: lane l holds A[row=l&15][k=(l>>4)*8+j]   (8 consecutive k -> b128 read)
//   B: lane l holds B[k=(l>>4)*8+j][col=l&15]   (needs k-contiguous storage)
//   D: lane l reg r holds D[row=(l>>4)*4+r][col=l&15]
// LDS: A[128][32], B^T[256][32] bf16, 16B-chunk XOR swizzle key (i^(i>>2))&3
// applied on BOTH write and read (rule 21) -> 2-way bank aliasing (free, m136).
__global__ __launch_bounds__(512) void k_final(
    const float* __restrict__ obs, const unsigned short* __restrict__ x1,
    const unsigned short* __restrict__ x2, const unsigned short* __restrict__ x3,
    const unsigned short* __restrict__ w1t, const float* __restrict__ b1,
    const float* __restrict__ bng, const float* __restrict__ bnb,
    const float* __restrict__ w2, float* __restrict__ logits)
{
  __shared__ unsigned short As[128 * 32];   // 8 KB
  __shared__ unsigned short Bs[256 * 32];   // 16 KB
  __shared__ float red[128][4];             // 2 KB (per-row partials by cg)
  const int t = threadIdx.x;
  const int row0 = blockIdx.x * 128;

  const int lane = t & 63, w = t >> 6;
  const int rg = w >> 2, cg = w & 3;        // wave tile: rows rg*64, cols cg*64
  const int kg8 = lane >> 4, lr = lane & 15;

  // staging decompositions (all 512 threads participate in both)
  const int ar_ = t >> 2, ach = t & 3;                 // A: row 0..127, k-chunk 0..3
  const int aswz = (ar_ ^ (ar_ >> 2)) & 3;
  const int bc_ = t >> 1, bhalf = t & 1;               // B: col 0..255, 16k-half
  const int bswz = (bc_ ^ (bc_ >> 2)) & 3;

  f32x4 acc[4][4];
  #pragma unroll
  for (int ai = 0; ai < 4; ++ai)
    #pragma unroll
    for (int bi = 0; bi < 4; ++bi)
      acc[ai][bi] = (f32x4){0.f, 0.f, 0.f, 0.f};

  const unsigned short* xsrc[3] = {x1, x2, x3};

  for (int step = 0; step < 13; ++step) {
    // ---- stage A tile [128 rows][32 k] ----
    if (step == 0) {                        // obs: fp32 -> bf16, zero-pad K
      float f[8];
      if (ach < 2) {
        const float* p = obs + (size_t)(row0 + ar_) * FIN + ach * 8;
        *(float4*)&f[0] = *(const float4*)p;
        *(float4*)&f[4] = *(const float4*)(p + 4);
      } else {
        #pragma unroll
        for (int j = 0; j < 8; ++j) f[j] = 0.f;      // zero-pad K 16->32
      }
      bf16x8 v;
      #pragma unroll
      for (int j = 0; j < 8; ++j) v[j] = (short)f2bf(f[j]);
      *(bf16x8*)&As[ar_ * 32 + ((ach ^ aswz) << 3)] = v;
    } else {                                // x: already bf16, raw copy
      const unsigned short* sp = xsrc[(step - 1) >> 2];
      const int soff = ((step - 1) & 3) * 32;
      *(uint4*)&As[ar_ * 32 + ((ach ^ aswz) << 3)] =
          *(const uint4*)(sp + (size_t)(row0 + ar_) * HID + soff + ach * 8);
    }
    // ---- stage B tile [256 cols][32 k] from pre-transposed w1t ----
    {
      const int kg = (step == 0) ? 0 : 16 + (step - 1) * 32;
      uint4 d0, d1;
      if (step == 0 && bhalf == 1) {
        d0 = make_uint4(0u, 0u, 0u, 0u); d1 = d0;       // zero-pad K 16->32
      } else {
        const unsigned short* p = w1t + (size_t)bc_ * 400 + kg + bhalf * 16;
        d0 = *(const uint4*)p;
        d1 = *(const uint4*)(p + 8);
      }
      const int ch0 = bhalf * 2;
      *(uint4*)&Bs[bc_ * 32 + ((ch0 ^ bswz) << 3)]       = d0;
      *(uint4*)&Bs[bc_ * 32 + (((ch0 + 1) ^ bswz) << 3)] = d1;
    }
    __syncthreads();

    bf16x8 af[4], bfr[4];
    #pragma unroll
    for (int ai = 0; ai < 4; ++ai) {
      const int row = rg * 64 + ai * 16 + lr;
      af[ai] = *(const bf16x8*)&As[row * 32 + ((kg8 ^ ((row ^ (row >> 2)) & 3)) << 3)];
    }
    #pragma unroll
    for (int bi = 0; bi < 4; ++bi) {
      const int col = cg * 64 + bi * 16 + lr;
      bfr[bi] = *(const bf16x8*)&Bs[col * 32 + ((kg8 ^ ((col ^ (col >> 2)) & 3)) << 3)];
    }
    #pragma unroll
    for (int ai = 0; ai < 4; ++ai)
      #pragma unroll
      for (int bi = 0; bi < 4; ++bi)
        acc[ai][bi] = __builtin_amdgcn_mfma_f32_16x16x32_bf16(
            af[ai], bfr[bi], acc[ai][bi], 0, 0, 0);
    __syncthreads();   // LDS reused next step
  }

  // ---- epilogue: bias + BN + ReLU + dot(w2), reduce 64 cols in-wave ----
  const float BNRS = 0.99999500003749969f;  // rsqrt(1 + 1e-5)
  float cb1[4], cscl[4], csft[4], cw2[4];
  #pragma unroll
  for (int bi = 0; bi < 4; ++bi) {
    const int c = cg * 64 + bi * 16 + lr;
    cb1[bi]  = b1[c];
    cscl[bi] = bng[c] * BNRS;
    csft[bi] = bnb[c];
    cw2[bi]  = w2[c];
  }
  #pragma unroll
  for (int ai = 0; ai < 4; ++ai) {
    #pragma unroll
    for (int rr = 0; rr < 4; ++rr) {
      float p = 0.f;
      #pragma unroll
      for (int bi = 0; bi < 4; ++bi) {
        const float h =
            fmaxf(fmaf(acc[ai][bi][rr] + cb1[bi], cscl[bi], csft[bi]), 0.f);
        p = fmaf(h, cw2[bi], p);
      }
      p += __shfl_xor(p, 1); p += __shfl_xor(p, 2);
      p += __shfl_xor(p, 4); p += __shfl_xor(p, 8);
      if (lr == 0) red[rg * 64 + ai * 16 + kg8 * 4 + rr][cg] = p;
    }
  }
  __syncthreads();
  if (t < 128)
    logits[row0 + t] = red[t][0] + red[t][1] + red[t][2] + red[t][3];
}

// ---------------- Softmax over nodes, with mask ------------------------------
// lin2_b is a uniform logit shift -> cancels in softmax (and is 0 anyway).
__global__ __launch_bounds__(256) void k_softmax(
    const float* __restrict__ logits, const int* __restrict__ mask,
    float* __restrict__ out)
{
  const int b = blockIdx.x, t = threadIdx.x;
  const int lane = t & 63, wave = t >> 6;
  __shared__ float red[4];
  float v[4];
  float mx = -3.0e38f;
  #pragma unroll
  for (int i = 0; i < 4; ++i) {
    const size_t idx = (size_t)b * NN + t + 256 * i;
    v[i] = (mask[idx] != 0) ? logits[idx] : -100000.0f;
    mx = fmaxf(mx, v[i]);
  }
  #pragma unroll
  for (int m = 1; m < 64; m <<= 1) mx = fmaxf(mx, __shfl_xor(mx, m));
  if (lane == 0) red[wave] = mx;
  __syncthreads();
  mx = fmaxf(fmaxf(red[0], red[1]), fmaxf(red[2], red[3]));
  __syncthreads();
  float s = 0.f;
  #pragma unroll
  for (int i = 0; i < 4; ++i) { v[i] = expf(v[i] - mx); s += v[i]; }
  #pragma unroll
  for (int m = 1; m < 64; m <<= 1) s += __shfl_xor(s, m);
  if (lane == 0) red[wave] = s;
  __syncthreads();
  s = red[0] + red[1] + red[2] + red[3];
  const float inv = 1.0f / s;
  #pragma unroll
  for (int i = 0; i < 4; ++i)
    out[(size_t)b * NN + t + 256 * i] = v[i] * inv;
}

extern "C" void kernel_launch(void* const* d_in, const int* in_sizes, int n_in,
                              void* d_out, int out_size, void* d_ws, size_t ws_size,
                              hipStream_t stream) {
  const float* obs = (const float*)d_in[0];
  const int*   msk = (const int*)  d_in[1];
  // d_in[2] edge_index: fixed grid, derived arithmetically.
  const float* c0w = (const float*)d_in[3];
  const float* c0b = (const float*)d_in[4];
  const float* l0g = (const float*)d_in[5];
  const float* l0b = (const float*)d_in[6];
  const float* c1w = (const float*)d_in[7];
  const float* c1b = (const float*)d_in[8];
  const float* l1g = (const float*)d_in[9];
  const float* l1b = (const float*)d_in[10];
  const float* c2w = (const float*)d_in[11];
  const float* c2b = (const float*)d_in[12];
  const float* l2g = (const float*)d_in[13];
  const float* l2b = (const float*)d_in[14];
  const float* w1  = (const float*)d_in[15];
  const float* b1  = (const float*)d_in[16];
  const float* bng = (const float*)d_in[17];
  const float* bnb = (const float*)d_in[18];
  const float* w2  = (const float*)d_in[19];
  // d_in[20] lin2_b: uniform logit shift, cancels in softmax.

  unsigned short* x1 = (unsigned short*)d_ws;              // bf16 [ROWS][128]
  unsigned short* x2 = x1 + (size_t)ROWS * HID;
  unsigned short* x3 = x2 + (size_t)ROWS * HID;
  float* logits      = (float*)(x3 + (size_t)ROWS * HID);  // f32 [ROWS]
  unsigned short* w1t = (unsigned short*)(logits + ROWS);  // bf16 [256][400]

  k_prep<<<256, 256, 0, stream>>>(w1, w1t);
  k_layer0<<<ROWS / 64, 256, 0, stream>>>(obs, c0w, c0b, l0g, l0b, x1);
  k_gin128<<<ROWS / 32, 256, 0, stream>>>(x1, c1w, c1b, l1g, l1b, x2);
  k_gin128<<<ROWS / 32, 256, 0, stream>>>(x2, c2w, c2b, l2g, l2b, x3);
  k_final<<<ROWS / 128, 512, 0, stream>>>(obs, x1, x2, x3, w1t, b1, bng, bnb,
                                          w2, logits);
  k_softmax<<<BATCH, 256, 0, stream>>>(logits, msk, (float*)d_out);
}

// Round 8
// 314.727 us; speedup vs baseline: 1.9415x; 1.9415x over previous
//
#include <hip/hip_runtime.h>

// NAGNNActor fused pipeline — all three GEMM-heavy stages now bf16-MFMA.
// Graph: fixed 32x32 grid 4-neighbor stencil (edge_index input ignored).
// GIN eps=-1 => agg = plain neighbor sum.
// ws layout (193.26 MiB):
//   x1[ROWS*128]bf16 | x2 | x3 | logits[ROWS]f32 | w1t[256*400]bf16
//   | g1t[128*128]bf16 | g2t[128*128]bf16
// Numerics: bf16 storage + bf16-in/fp32-acc MFMA everywhere; LN renormalizes
// per layer; r4 measured absmax 3.05e-5 with the k_final MFMA path.

namespace {
constexpr int NN = 1024;          // nodes per sample (32x32)
constexpr int BATCH = 256;
constexpr int FIN = 16;
constexpr int HID = 128;
constexpr int ROWS = BATCH * NN;  // 262144
}

typedef __attribute__((ext_vector_type(8))) short bf16x8;   // 8 bf16 = 4 VGPR
typedef __attribute__((ext_vector_type(4))) float f32x4;

__device__ inline unsigned short f2bf(float f) {  // RNE fp32->bf16
  union { float f; unsigned u; } v; v.f = f;
  unsigned r = v.u + 0x7FFFu + ((v.u >> 16) & 1u);
  return (unsigned short)(r >> 16);
}

// ---- Prepass: transpose+cvt weights to bf16 col-major (k contiguous) --------
// blocks 0..255: w1t[256][400] from w1[400][256]
// blocks 256..383: g1t[128][128] from conv1_w[128][128]
// blocks 384..511: g2t[128][128] from conv2_w[128][128]
__global__ __launch_bounds__(256) void k_prep(
    const float* __restrict__ w1, const float* __restrict__ gw1,
    const float* __restrict__ gw2, unsigned short* __restrict__ w1t,
    unsigned short* __restrict__ g1t, unsigned short* __restrict__ g2t)
{
  const int bb = blockIdx.x, t = threadIdx.x;
  if (bb < 256) {
    for (int k = t; k < 400; k += 256)
      w1t[(size_t)bb * 400 + k] = f2bf(w1[(size_t)k * 256 + bb]);
  } else if (bb < 384) {
    const int c = bb - 256;
    for (int k = t; k < 128; k += 256)
      g1t[(size_t)c * 128 + k] = f2bf(gw1[(size_t)k * 128 + c]);
  } else {
    const int c = bb - 384;
    for (int k = t; k < 128; k += 256)
      g2t[(size_t)c * 128 + k] = f2bf(gw2[(size_t)k * 128 + c]);
  }
}

// ---------------- Layer 0: stencil(obs) @ W0[16,128] + LN + ReLU -------------
// 64 rows/block, 256 thr. K=16 is too small for MFMA to matter; memory-bound.
__global__ __launch_bounds__(256) void k_layer0(
    const float* __restrict__ obs,
    const float* __restrict__ w,  const float* __restrict__ bias,
    const float* __restrict__ g,  const float* __restrict__ be,
    unsigned short* __restrict__ xout)
{
  __shared__ float aggs[64][FIN];   // 4 KB
  const int t = threadIdx.x;
  const int lane = t & 63, wave = t >> 6;
  const int row0 = blockIdx.x * 64;
  const int b = row0 >> 10;
  const int n0 = row0 & (NN - 1);

  {  // stage stencil sums: one float4 per thread ([64 rows][4 quads])
    const int rl = t >> 2;
    const int kq = (t & 3) * 4;
    const int n = n0 + rl;
    const int gi = n >> 5, gj = n & 31;
    const float* base = obs + (size_t)b * NN * FIN + kq;
    float4 s = make_float4(0.f, 0.f, 0.f, 0.f);
    if (gj > 0)  { float4 v = *(const float4*)(base + (size_t)(n - 1)  * FIN); s.x += v.x; s.y += v.y; s.z += v.z; s.w += v.w; }
    if (gj < 31) { float4 v = *(const float4*)(base + (size_t)(n + 1)  * FIN); s.x += v.x; s.y += v.y; s.z += v.z; s.w += v.w; }
    if (gi > 0)  { float4 v = *(const float4*)(base + (size_t)(n - 32) * FIN); s.x += v.x; s.y += v.y; s.z += v.z; s.w += v.w; }
    if (gi < 31) { float4 v = *(const float4*)(base + (size_t)(n + 32) * FIN); s.x += v.x; s.y += v.y; s.z += v.z; s.w += v.w; }
    *(float4*)&aggs[rl][kq] = s;
  }

  const int c0 = lane, c1 = lane + 64;
  float wr0[FIN], wr1[FIN];
  #pragma unroll
  for (int k = 0; k < FIN; ++k) { wr0[k] = w[k * HID + c0]; wr1[k] = w[k * HID + c1]; }
  const float bias0 = bias[c0], bias1 = bias[c1];
  const float gg0 = g[c0], gg1 = g[c1], bb0 = be[c0], bb1 = be[c1];
  __syncthreads();

  #pragma unroll 4
  for (int rr = 0; rr < 16; ++rr) {
    const int rl = wave * 16 + rr;
    float y0 = bias0, y1 = bias1;
    #pragma unroll
    for (int kq = 0; kq < FIN; kq += 4) {
      float4 a = *(const float4*)&aggs[rl][kq];
      y0 = fmaf(a.x, wr0[kq+0], y0);  y1 = fmaf(a.x, wr1[kq+0], y1);
      y0 = fmaf(a.y, wr0[kq+1], y0);  y1 = fmaf(a.y, wr1[kq+1], y1);
      y0 = fmaf(a.z, wr0[kq+2], y0);  y1 = fmaf(a.z, wr1[kq+2], y1);
      y0 = fmaf(a.w, wr0[kq+3], y0);  y1 = fmaf(a.w, wr1[kq+3], y1);
    }
    float s = y0 + y1, ss = y0 * y0 + y1 * y1;
    #pragma unroll
    for (int m = 1; m < 64; m <<= 1) { s += __shfl_xor(s, m); ss += __shfl_xor(ss, m); }
    const float mu  = s * (1.f / 128.f);
    const float var = ss * (1.f / 128.f) - mu * mu;
    const float inv = rsqrtf(var + 1e-5f);
    const float o0 = fmaxf(fmaf((y0 - mu) * inv, gg0, bb0), 0.f);
    const float o1 = fmaxf(fmaf((y1 - mu) * inv, gg1, bb1), 0.f);
    unsigned short* op = xout + (size_t)(row0 + rl) * HID;
    op[c0] = f2bf(o0); op[c1] = f2bf(o1);
  }
}

// -------- Layers 1/2 (bf16 MFMA): stencil(x) @ W[128,128] + LN + ReLU --------
// 2048 blocks x 512 thr (8 waves). Block: 128 rows x 128 cols (full HID).
// Wave w owns rows w*16..+15, ALL 128 cols -> LN is wave-local.
// Per K-step (4 total): 1 A-frag + 8 B-frags -> 8 mfma_f32_16x16x32_bf16.
// LDS: Agg[128][128] bf16 + Wt[128][128] bf16 = 64 KB -> 2 blocks/CU.
// Swizzle: 16B chunk index ch (0..15 per 256B row) stored at ch^(row&7).
// Frag reads then hit all 8 4-bank groups evenly (8 lanes each, distinct
// addrs) = minimum aliasing for wave64 b128; same involution on write+read.
// MFMA layouts (validated on HW by k_final r4, absmax 3e-5):
//   A: lane l holds A[row=l&15][k=(l>>4)*8+j]
//   B: lane l holds B[k=(l>>4)*8+j][col=l&15]
//   D: lane l reg r holds D[row=(l>>4)*4+r][col=l&15]
__global__ __launch_bounds__(512) void k_gin_mfma(
    const unsigned short* __restrict__ xin, const unsigned short* __restrict__ wt,
    const float* __restrict__ bias, const float* __restrict__ g,
    const float* __restrict__ be, unsigned short* __restrict__ xout)
{
  __shared__ unsigned short Agg[128 * 128];  // 32 KB
  __shared__ unsigned short Wt[128 * 128];   // 32 KB
  const int t = threadIdx.x;
  const int row0 = blockIdx.x * 128;
  const int b = row0 >> 10, n0 = row0 & (NN - 1);

  // ---- stage Wt[col][k] (bf16, already transposed) ----
  {
    const int col = t >> 2;
    const int ch0 = (t & 3) * 4;
    const unsigned short* p = wt + (size_t)col * 128 + ch0 * 8;
    #pragma unroll
    for (int i = 0; i < 4; ++i) {
      const int ch = ch0 + i;
      *(uint4*)&Wt[col * 128 + ((ch ^ (col & 7)) << 3)] =
          *(const uint4*)(p + i * 8);
    }
  }
  // ---- stage Agg: stencil sums (fp32 accum) -> bf16, swizzled ----
  {
    const int rl = t >> 2;           // 0..127
    const int kb = (t & 3) * 32;     // k base
    const int n = n0 + rl;
    const int gi = n >> 5, gj = n & 31;
    const unsigned short* base = xin + (size_t)b * NN * HID + kb;
    float s[32];
    #pragma unroll
    for (int j = 0; j < 32; ++j) s[j] = 0.f;
    auto addn = [&](int nb) {
      const unsigned short* p = base + (size_t)nb * HID;
      #pragma unroll
      for (int c = 0; c < 4; ++c) {
        const uint4 u = *(const uint4*)(p + c * 8);
        const unsigned uu[4] = {u.x, u.y, u.z, u.w};
        #pragma unroll
        for (int j = 0; j < 4; ++j) {
          union { unsigned v; float f; } lo, hi;
          lo.v = uu[j] << 16;
          hi.v = uu[j] & 0xFFFF0000u;
          s[c * 8 + 2 * j]     += lo.f;
          s[c * 8 + 2 * j + 1] += hi.f;
        }
      }
    };
    if (gj > 0)  addn(n - 1);
    if (gj < 31) addn(n + 1);
    if (gi > 0)  addn(n - 32);
    if (gi < 31) addn(n + 32);
    #pragma unroll
    for (int c = 0; c < 4; ++c) {
      bf16x8 v;
      #pragma unroll
      for (int j = 0; j < 8; ++j) v[j] = (short)f2bf(s[c * 8 + j]);
      const int ch = (t & 3) * 4 + c;
      *(bf16x8*)&Agg[rl * 128 + ((ch ^ (rl & 7)) << 3)] = v;
    }
  }
  __syncthreads();

  // ---- MFMA: wave w = rows w*16..+15 x 128 cols ----
  const int lane = t & 63, w = t >> 6;
  const int lr = lane & 15, q = lane >> 4;
  const int rbase = w * 16;

  f32x4 acc[8];
  #pragma unroll
  for (int bi = 0; bi < 8; ++bi) acc[bi] = (f32x4){0.f, 0.f, 0.f, 0.f};

  #pragma unroll
  for (int kk = 0; kk < 4; ++kk) {
    const int ach = kk * 4 + q;
    const int arow = rbase + lr;
    const bf16x8 af =
        *(const bf16x8*)&Agg[arow * 128 + ((ach ^ (arow & 7)) << 3)];
    #pragma unroll
    for (int bi = 0; bi < 8; ++bi) {
      const int col = bi * 16 + lr;
      const bf16x8 bf_ =
          *(const bf16x8*)&Wt[col * 128 + ((ach ^ (col & 7)) << 3)];
      acc[bi] = __builtin_amdgcn_mfma_f32_16x16x32_bf16(af, bf_, acc[bi], 0, 0, 0);
    }
  }

  // ---- epilogue: bias + LN (wave-local, 16-lane reduce) + ReLU -> bf16 ----
  float cb[8], cg_[8], cbe[8];
  #pragma unroll
  for (int bi = 0; bi < 8; ++bi) {
    const int c = bi * 16 + lr;
    cb[bi] = bias[c]; cg_[bi] = g[c]; cbe[bi] = be[c];
  }
  #pragma unroll
  for (int r = 0; r < 4; ++r) {
    float s = 0.f, ss = 0.f;
    #pragma unroll
    for (int bi = 0; bi < 8; ++bi) {
      const float y = acc[bi][r] + cb[bi];
      s += y; ss += y * y;
    }
    #pragma unroll
    for (int m = 1; m < 16; m <<= 1) {   // row lives in one 16-lane group
      s += __shfl_xor(s, m); ss += __shfl_xor(ss, m);
    }
    const float mu  = s * (1.f / 128.f);
    const float var = ss * (1.f / 128.f) - mu * mu;
    const float inv = rsqrtf(var + 1e-5f);
    unsigned short* op = xout + (size_t)(row0 + rbase + q * 4 + r) * HID + lr;
    #pragma unroll
    for (int bi = 0; bi < 8; ++bi) {
      const float y = acc[bi][r] + cb[bi];
      const float o = fmaxf(fmaf((y - mu) * inv, cg_[bi], cbe[bi]), 0.f);
      op[bi * 16] = f2bf(o);
    }
  }
}

// ------- Final (bf16 MFMA): concat[obs,x1,x2,x3] @ lin1 + BN + ReLU + lin2 ---
// 2048 blocks x 512 thr. Block: 128 rows x 256 cols, writes FULL logits.
// (unchanged from r4 — validated, absmax 3.05e-5)
__global__ __launch_bounds__(512) void k_final(
    const float* __restrict__ obs, const unsigned short* __restrict__ x1,
    const unsigned short* __restrict__ x2, const unsigned short* __restrict__ x3,
    const unsigned short* __restrict__ w1t, const float* __restrict__ b1,
    const float* __restrict__ bng, const float* __restrict__ bnb,
    const float* __restrict__ w2, float* __restrict__ logits)
{
  __shared__ unsigned short As[128 * 32];   // 8 KB
  __shared__ unsigned short Bs[256 * 32];   // 16 KB
  __shared__ float red[128][4];             // 2 KB (per-row partials by cg)
  const int t = threadIdx.x;
  const int row0 = blockIdx.x * 128;

  const int lane = t & 63, w = t >> 6;
  const int rg = w >> 2, cg = w & 3;        // wave tile: rows rg*64, cols cg*64
  const int kg8 = lane >> 4, lr = lane & 15;

  const int ar_ = t >> 2, ach = t & 3;                 // A: row 0..127, k-chunk
  const int aswz = (ar_ ^ (ar_ >> 2)) & 3;
  const int bc_ = t >> 1, bhalf = t & 1;               // B: col 0..255, 16k-half
  const int bswz = (bc_ ^ (bc_ >> 2)) & 3;

  f32x4 acc[4][4];
  #pragma unroll
  for (int ai = 0; ai < 4; ++ai)
    #pragma unroll
    for (int bi = 0; bi < 4; ++bi)
      acc[ai][bi] = (f32x4){0.f, 0.f, 0.f, 0.f};

  const unsigned short* xsrc[3] = {x1, x2, x3};

  for (int step = 0; step < 13; ++step) {
    // ---- stage A tile [128 rows][32 k] ----
    if (step == 0) {                        // obs: fp32 -> bf16, zero-pad K
      float f[8];
      if (ach < 2) {
        const float* p = obs + (size_t)(row0 + ar_) * FIN + ach * 8;
        *(float4*)&f[0] = *(const float4*)p;
        *(float4*)&f[4] = *(const float4*)(p + 4);
      } else {
        #pragma unroll
        for (int j = 0; j < 8; ++j) f[j] = 0.f;      // zero-pad K 16->32
      }
      bf16x8 v;
      #pragma unroll
      for (int j = 0; j < 8; ++j) v[j] = (short)f2bf(f[j]);
      *(bf16x8*)&As[ar_ * 32 + ((ach ^ aswz) << 3)] = v;
    } else {                                // x: already bf16, raw copy
      const unsigned short* sp = xsrc[(step - 1) >> 2];
      const int soff = ((step - 1) & 3) * 32;
      *(uint4*)&As[ar_ * 32 + ((ach ^ aswz) << 3)] =
          *(const uint4*)(sp + (size_t)(row0 + ar_) * HID + soff + ach * 8);
    }
    // ---- stage B tile [256 cols][32 k] from pre-transposed w1t ----
    {
      const int kg = (step == 0) ? 0 : 16 + (step - 1) * 32;
      uint4 d0, d1;
      if (step == 0 && bhalf == 1) {
        d0 = make_uint4(0u, 0u, 0u, 0u); d1 = d0;       // zero-pad K 16->32
      } else {
        const unsigned short* p = w1t + (size_t)bc_ * 400 + kg + bhalf * 16;
        d0 = *(const uint4*)p;
        d1 = *(const uint4*)(p + 8);
      }
      const int ch0 = bhalf * 2;
      *(uint4*)&Bs[bc_ * 32 + ((ch0 ^ bswz) << 3)]       = d0;
      *(uint4*)&Bs[bc_ * 32 + (((ch0 + 1) ^ bswz) << 3)] = d1;
    }
    __syncthreads();

    bf16x8 af[4], bfr[4];
    #pragma unroll
    for (int ai = 0; ai < 4; ++ai) {
      const int row = rg * 64 + ai * 16 + lr;
      af[ai] = *(const bf16x8*)&As[row * 32 + ((kg8 ^ ((row ^ (row >> 2)) & 3)) << 3)];
    }
    #pragma unroll
    for (int bi = 0; bi < 4; ++bi) {
      const int col = cg * 64 + bi * 16 + lr;
      bfr[bi] = *(const bf16x8*)&Bs[col * 32 + ((kg8 ^ ((col ^ (col >> 2)) & 3)) << 3)];
    }
    #pragma unroll
    for (int ai = 0; ai < 4; ++ai)
      #pragma unroll
      for (int bi = 0; bi < 4; ++bi)
        acc[ai][bi] = __builtin_amdgcn_mfma_f32_16x16x32_bf16(
            af[ai], bfr[bi], acc[ai][bi], 0, 0, 0);
    __syncthreads();   // LDS reused next step
  }

  // ---- epilogue: bias + BN + ReLU + dot(w2), reduce 64 cols in-wave ----
  const float BNRS = 0.99999500003749969f;  // rsqrt(1 + 1e-5)
  float cb1[4], cscl[4], csft[4], cw2[4];
  #pragma unroll
  for (int bi = 0; bi < 4; ++bi) {
    const int c = cg * 64 + bi * 16 + lr;
    cb1[bi]  = b1[c];
    cscl[bi] = bng[c] * BNRS;
    csft[bi] = bnb[c];
    cw2[bi]  = w2[c];
  }
  #pragma unroll
  for (int ai = 0; ai < 4; ++ai) {
    #pragma unroll
    for (int rr = 0; rr < 4; ++rr) {
      float p = 0.f;
      #pragma unroll
      for (int bi = 0; bi < 4; ++bi) {
        const float h =
            fmaxf(fmaf(acc[ai][bi][rr] + cb1[bi], cscl[bi], csft[bi]), 0.f);
        p = fmaf(h, cw2[bi], p);
      }
      p += __shfl_xor(p, 1); p += __shfl_xor(p, 2);
      p += __shfl_xor(p, 4); p += __shfl_xor(p, 8);
      if (lr == 0) red[rg * 64 + ai * 16 + kg8 * 4 + rr][cg] = p;
    }
  }
  __syncthreads();
  if (t < 128)
    logits[row0 + t] = red[t][0] + red[t][1] + red[t][2] + red[t][3];
}

// ---------------- Softmax over nodes, with mask ------------------------------
__global__ __launch_bounds__(256) void k_softmax(
    const float* __restrict__ logits, const int* __restrict__ mask,
    float* __restrict__ out)
{
  const int b = blockIdx.x, t = threadIdx.x;
  const int lane = t & 63, wave = t >> 6;
  __shared__ float red[4];
  float v[4];
  float mx = -3.0e38f;
  #pragma unroll
  for (int i = 0; i < 4; ++i) {
    const size_t idx = (size_t)b * NN + t + 256 * i;
    v[i] = (mask[idx] != 0) ? logits[idx] : -100000.0f;
    mx = fmaxf(mx, v[i]);
  }
  #pragma unroll
  for (int m = 1; m < 64; m <<= 1) mx = fmaxf(mx, __shfl_xor(mx, m));
  if (lane == 0) red[wave] = mx;
  __syncthreads();
  mx = fmaxf(fmaxf(red[0], red[1]), fmaxf(red[2], red[3]));
  __syncthreads();
  float s = 0.f;
  #pragma unroll
  for (int i = 0; i < 4; ++i) { v[i] = expf(v[i] - mx); s += v[i]; }
  #pragma unroll
  for (int m = 1; m < 64; m <<= 1) s += __shfl_xor(s, m);
  if (lane == 0) red[wave] = s;
  __syncthreads();
  s = red[0] + red[1] + red[2] + red[3];
  const float inv = 1.0f / s;
  #pragma unroll
  for (int i = 0; i < 4; ++i)
    out[(size_t)b * NN + t + 256 * i] = v[i] * inv;
}

extern "C" void kernel_launch(void* const* d_in, const int* in_sizes, int n_in,
                              void* d_out, int out_size, void* d_ws, size_t ws_size,
                              hipStream_t stream) {
  const float* obs = (const float*)d_in[0];
  const int*   msk = (const int*)  d_in[1];
  // d_in[2] edge_index: fixed grid, derived arithmetically.
  const float* c0w = (const float*)d_in[3];
  const float* c0b = (const float*)d_in[4];
  const float* l0g = (const float*)d_in[5];
  const float* l0b = (const float*)d_in[6];
  const float* c1w = (const float*)d_in[7];
  const float* c1b = (const float*)d_in[8];
  const float* l1g = (const float*)d_in[9];
  const float* l1b = (const float*)d_in[10];
  const float* c2w = (const float*)d_in[11];
  const float* c2b = (const float*)d_in[12];
  const float* l2g = (const float*)d_in[13];
  const float* l2b = (const float*)d_in[14];
  const float* w1  = (const float*)d_in[15];
  const float* b1  = (const float*)d_in[16];
  const float* bng = (const float*)d_in[17];
  const float* bnb = (const float*)d_in[18];
  const float* w2  = (const float*)d_in[19];
  // d_in[20] lin2_b: uniform logit shift, cancels in softmax.

  unsigned short* x1 = (unsigned short*)d_ws;              // bf16 [ROWS][128]
  unsigned short* x2 = x1 + (size_t)ROWS * HID;
  unsigned short* x3 = x2 + (size_t)ROWS * HID;
  float* logits      = (float*)(x3 + (size_t)ROWS * HID);  // f32 [ROWS]
  unsigned short* w1t = (unsigned short*)(logits + ROWS);  // bf16 [256][400]
  unsigned short* g1t = w1t + (size_t)256 * 400;           // bf16 [128][128]
  unsigned short* g2t = g1t + (size_t)128 * 128;           // bf16 [128][128]

  k_prep<<<512, 256, 0, stream>>>(w1, c1w, c2w, w1t, g1t, g2t);
  k_layer0<<<ROWS / 64, 256, 0, stream>>>(obs, c0w, c0b, l0g, l0b, x1);
  k_gin_mfma<<<ROWS / 128, 512, 0, stream>>>(x1, g1t, c1b, l1g, l1b, x2);
  k_gin_mfma<<<ROWS / 128, 512, 0, stream>>>(x2, g2t, c2b, l2g, l2b, x3);
  k_final<<<ROWS / 128, 512, 0, stream>>>(obs, x1, x2, x3, w1t, b1, bng, bnb,
                                          w2, logits);
  k_softmax<<<BATCH, 256, 0, stream>>>(logits, msk, (float*)d_out);
}